// Round 7
// baseline (259.865 us; speedup 1.0000x reference)
//
#include <hip/hip_runtime.h>
#include <math.h>

typedef __bf16 bf16x8 __attribute__((ext_vector_type(8)));
typedef __bf16 bf16x4 __attribute__((ext_vector_type(4)));
typedef float f32x4 __attribute__((ext_vector_type(4)));

#define HDIM 128
#define TPTS 64        // points per block (4 waves x 16)
#define NTHREADS 256

#define EMV 0.001f
#define LFIX 0.05f
#define KFIX 100.0f
#define LAMBDA_L 0.5769230769230769f
#define MU_L 0.3846153846153846f

// swizzled bf16 index within a 128-wide-row image; blk = 16B granule in [0,16)
__device__ __forceinline__ int swb(int r, int blk) {
    return (r << 7) + ((blk ^ (r & 7)) << 3);
}

__device__ __forceinline__ float fast_tanh(float x) {
    float xc = fminf(fmaxf(x, -10.f), 10.f);
    float e = __expf(2.f * xc);
    return (e - 1.f) / (e + 1.f);
}

__device__ __forceinline__ float wred(float v) {
#pragma unroll
    for (int off = 32; off > 0; off >>= 1) v += __shfl_down(v, off, 64);
    return v;
}

// Wave-private forward GEMM over this wave's 16 points.
// out[p][n] = sum_j in[p][j]*W[j][n]; WT = W^T image in LDS (shared, read-only).
// buf0 -> tanh(acc+bias); bufs 1..NB-1 -> acc*(1-h^2), h local fp32. In-place safe
// within the wave: all B-frags are register-resident before epilogue writes.
template <int NB>
__device__ __forceinline__ void wgemm_fwd(const __bf16* WT, __bf16* const* sl,
                                          const float* __restrict__ biasg, int lane) {
    const int l15 = lane & 15, q = lane >> 4;
    bf16x8 bfr[NB][4];
#pragma unroll
    for (int b = 0; b < NB; ++b)
#pragma unroll
        for (int ks = 0; ks < 4; ++ks)
            bfr[b][ks] = *(const bf16x8*)(sl[b] + swb(l15, ks * 4 + q));
    f32x4 acc[NB][8];
#pragma unroll
    for (int b = 0; b < NB; ++b)
#pragma unroll
        for (int nt = 0; nt < 8; ++nt) acc[b][nt] = (f32x4){0.f, 0.f, 0.f, 0.f};
#pragma unroll
    for (int nt = 0; nt < 8; ++nt) {
#pragma unroll
        for (int ks = 0; ks < 4; ++ks) {
            bf16x8 a = *(const bf16x8*)(WT + swb(nt * 16 + l15, ks * 4 + q));
#pragma unroll
            for (int b = 0; b < NB; ++b)
                acc[b][nt] = __builtin_amdgcn_mfma_f32_16x16x32_bf16(a, bfr[b][ks], acc[b][nt], 0, 0, 0);
        }
    }
#pragma unroll
    for (int nt = 0; nt < 8; ++nt) {
        const int n0 = nt * 16 + q * 4;
        float4 bv = *(const float4*)(biasg + n0);
        float bias4[4] = {bv.x, bv.y, bv.z, bv.w};
        float fct[4];
        bf16x4 hv;
#pragma unroll
        for (int i = 0; i < 4; ++i) {
            float h = fast_tanh(acc[0][nt][i] + bias4[i]);
            hv[i] = (__bf16)h;
            fct[i] = 1.f - h * h;
        }
        const int widx = swb(l15, n0 >> 3) + (n0 & 7);
        *(bf16x4*)(sl[0] + widx) = hv;
#pragma unroll
        for (int b = 1; b < NB; ++b) {
            bf16x4 ov;
#pragma unroll
            for (int i = 0; i < 4; ++i) ov[i] = (__bf16)(acc[b][nt][i] * fct[i]);
            *(bf16x4*)(sl[b] + widx) = ov;
        }
    }
}

// Wave-private backward GEMM (trace): out[p][j] = sum_k in[p][k]*Wg[j][k].
// A-frags straight from global fp32 (rare tiles, L2-hot). Epilogue *(1-href^2).
template <int NB>
__device__ __forceinline__ void wgemm_bwd(const float* __restrict__ Wg,
                                          __bf16* const* sl, const __bf16* href, int lane) {
    const int l15 = lane & 15, q = lane >> 4;
    bf16x8 bfr[NB][4];
#pragma unroll
    for (int b = 0; b < NB; ++b)
#pragma unroll
        for (int ks = 0; ks < 4; ++ks)
            bfr[b][ks] = *(const bf16x8*)(sl[b] + swb(l15, ks * 4 + q));
    f32x4 acc[NB][8];
#pragma unroll
    for (int b = 0; b < NB; ++b)
#pragma unroll
        for (int nt = 0; nt < 8; ++nt) acc[b][nt] = (f32x4){0.f, 0.f, 0.f, 0.f};
#pragma unroll
    for (int nt = 0; nt < 8; ++nt) {
        const int j = nt * 16 + l15;
#pragma unroll
        for (int ks = 0; ks < 4; ++ks) {
            const float4* s = (const float4*)(Wg + j * HDIM + (ks * 4 + q) * 8);
            float4 v0 = s[0], v1 = s[1];
            bf16x8 a = {(__bf16)v0.x, (__bf16)v0.y, (__bf16)v0.z, (__bf16)v0.w,
                        (__bf16)v1.x, (__bf16)v1.y, (__bf16)v1.z, (__bf16)v1.w};
#pragma unroll
            for (int b = 0; b < NB; ++b)
                acc[b][nt] = __builtin_amdgcn_mfma_f32_16x16x32_bf16(a, bfr[b][ks], acc[b][nt], 0, 0, 0);
        }
    }
#pragma unroll
    for (int nt = 0; nt < 8; ++nt) {
        const int n0 = nt * 16 + q * 4;
        const int widx = swb(l15, n0 >> 3) + (n0 & 7);
        bf16x4 hv = *(const bf16x4*)(href + widx);
#pragma unroll
        for (int b = 0; b < NB; ++b) {
            bf16x4 ov;
#pragma unroll
            for (int i = 0; i < 4; ++i) {
                float h = (float)hv[i];
                ov[i] = (__bf16)(acc[b][nt][i] * (1.f - h * h));
            }
            *(bf16x4*)(sl[b] + widx) = ov;
        }
    }
}

// per-point squared-norm of a wave slice; valid on lanes q==0 (p = lane&15)
__device__ __forceinline__ float wnorm(const __bf16* s, int lane) {
    const int l15 = lane & 15, q = lane >> 4;
    float v = 0.f;
#pragma unroll
    for (int g = 0; g < 4; ++g) {
        bf16x8 x = *(const bf16x8*)(s + swb(l15, q * 4 + g));
#pragma unroll
        for (int e = 0; e < 8; ++e) { float f = (float)x[e]; v += f * f; }
    }
    v += __shfl_down(v, 16, 64);
    v += __shfl_down(v, 32, 64);
    return v;
}

__global__ void __launch_bounds__(NTHREADS, 1) pinn_all(
    const float* __restrict__ xPhys, const float* __restrict__ coord,
    const float* __restrict__ W1, const float* __restrict__ b1,
    const float* __restrict__ W2, const float* __restrict__ b2,
    const float* __restrict__ W3, const float* __restrict__ b3,
    const float* __restrict__ W4, const float* __restrict__ b4,
    const float* __restrict__ fc, const float* __restrict__ Fv,
    const int* __restrict__ nfixp,
    float* __restrict__ energy_c_out, float* __restrict__ u_out,
    float* __restrict__ acc, int nmain) {
    __shared__ __align__(16) __bf16 W2Ts[HDIM * HDIM];        // 32 KB
    __shared__ __align__(16) __bf16 W3Ts[HDIM * HDIM];        // 32 KB
    __shared__ __align__(16) __bf16 arena[4 * 4 * 16 * HDIM]; // 64 KB: [wave][buf]
    __shared__ __align__(16) __bf16 hist[2 * 16 * HDIM];      // 8 KB (trace h1,h2)
    __shared__ float W1s[3 * HDIM], b1s[HDIM];                // 2 KB
    __shared__ float xs[4 * 16 * 4];                          // 1 KB: x0,x1,x2,xp3

    const int tid = threadIdx.x;
    const int lane = tid & 63, wid = tid >> 6, l15 = lane & 15, q = lane >> 4;
    const int bi = blockIdx.x;
    const int nfixv = nfixp[0];
    const bool is_force = bi >= nmain;

    // ---------- one-time staging (single barrier) ----------
    {
        const int n = tid & 127;
        const int jb = (tid >> 7) * 64;
#pragma unroll
        for (int jj = 0; jj < 64; jj += 4) {
            int j0 = jb + jj;
            bf16x4 p2 = {(__bf16)W2[(j0 + 0) * HDIM + n], (__bf16)W2[(j0 + 1) * HDIM + n],
                         (__bf16)W2[(j0 + 2) * HDIM + n], (__bf16)W2[(j0 + 3) * HDIM + n]};
            bf16x4 p3 = {(__bf16)W3[(j0 + 0) * HDIM + n], (__bf16)W3[(j0 + 1) * HDIM + n],
                         (__bf16)W3[(j0 + 2) * HDIM + n], (__bf16)W3[(j0 + 3) * HDIM + n]};
            int o = swb(n, j0 >> 3) + (j0 & 7);
            *(bf16x4*)(W2Ts + o) = p2;
            *(bf16x4*)(W3Ts + o) = p3;
        }
        for (int e = tid; e < 3 * HDIM; e += NTHREADS) W1s[e] = W1[e];   // FIXED: full 384
        if (tid < HDIM) b1s[tid] = b1[tid];                              // FIXED: was never loaded
    }
    // W4 A-fragments in registers (padded W4^T rows 3..15 = 0)
    bf16x8 w4f[4];
#pragma unroll
    for (int ks = 0; ks < 4; ++ks) {
#pragma unroll
        for (int e = 0; e < 8; ++e) {
            int k = ks * 32 + q * 8 + e;
            float v = (l15 < 3) ? W4[k * 3 + l15] : 0.f;
            w4f[ks][e] = (__bf16)v;
        }
    }
    __syncthreads();   // the only block barrier

    // ---------- per-wave setup ----------
    const int base = (is_force ? (bi - nmain) : bi) * TPTS;
    const int wp0 = base + wid * 16;           // this wave's first point
    __bf16* sl[4];
#pragma unroll
    for (int b = 0; b < 4; ++b) sl[b] = arena + (wid * 4 + b) * (16 * HDIM);
    float* xw = xs + wid * 64;

    if (q == 0) {   // 16 lanes load this wave's coords (+xp^3)
        const float* cp = is_force ? fc : coord;
        xw[l15 * 4 + 0] = cp[(wp0 + l15) * 3 + 0];
        xw[l15 * 4 + 1] = cp[(wp0 + l15) * 3 + 1];
        xw[l15 * 4 + 2] = cp[(wp0 + l15) * 3 + 2];
        float xp = is_force ? 0.f : xPhys[wp0 + l15];
        xw[l15 * 4 + 3] = xp * xp * xp;
    }

    if (!is_force) {
        const bool fullfix = (base + TPTS) <= nfixv;
        const bool fullrr = base >= nfixv;
        const bool do_trace = (wid == 0) && (fullfix ? true : (fullrr ? ((bi & 15) == 4) : true));

        // ---- layer 1 + tangent seeds (wave-private) ----
#pragma unroll
        for (int it = 0; it < 4; ++it) {
            int f = lane + it * 64;
            int p = f >> 4, blk = f & 15, j0 = blk * 8;
            float x0 = xw[p * 4 + 0], x1 = xw[p * 4 + 1], x2 = xw[p * 4 + 2];
            bf16x8 hv, t0v, t1v, t2v;
#pragma unroll
            for (int jj = 0; jj < 8; ++jj) {
                int j = j0 + jj;
                float w0 = W1s[j], w1 = W1s[HDIM + j], w2 = W1s[2 * HDIM + j];
                float z = b1s[j] + x0 * w0 + x1 * w1 + x2 * w2;
                float h = fast_tanh(z);
                float fct = 1.f - h * h;
                hv[jj] = (__bf16)h;
                t0v[jj] = (__bf16)(fct * w0);
                t1v[jj] = (__bf16)(fct * w1);
                t2v[jj] = (__bf16)(fct * w2);
            }
            int wi = swb(p, blk);
            *(bf16x8*)(sl[0] + wi) = hv;
            *(bf16x8*)(sl[1] + wi) = t0v;
            *(bf16x8*)(sl[2] + wi) = t1v;
            *(bf16x8*)(sl[3] + wi) = t2v;
        }
        if (do_trace) {  // preserve h1
#pragma unroll
            for (int it = 0; it < 4; ++it)
                ((bf16x8*)hist)[lane + it * 64] = ((const bf16x8*)sl[0])[lane + it * 64];
        }
        wgemm_fwd<4>(W2Ts, sl, b2, lane);     // h2 over h1; tangents in place
        if (do_trace) {  // preserve h2
#pragma unroll
            for (int it = 0; it < 4; ++it)
                ((bf16x8*)(hist + 16 * HDIM))[lane + it * 64] = ((const bf16x8*)sl[0])[lane + it * 64];
        }
        wgemm_fwd<4>(W3Ts, sl, b3, lane);     // h3 over h2

        // ---- head: u + Jacobian columns ----
        f32x4 ha[4];
#pragma unroll
        for (int b = 0; b < 4; ++b) ha[b] = (f32x4){0.f, 0.f, 0.f, 0.f};
#pragma unroll
        for (int ks = 0; ks < 4; ++ks) {
#pragma unroll
            for (int b = 0; b < 4; ++b) {
                bf16x8 bf_ = *(const bf16x8*)(sl[b] + swb(l15, ks * 4 + q));
                ha[b] = __builtin_amdgcn_mfma_f32_16x16x32_bf16(w4f[ks], bf_, ha[b], 0, 0, 0);
            }
        }
        // ---- per-point outputs + energy (q==0 lanes: p = l15) ----
        float er = 0.f, ef = 0.f;
        if (q == 0) {
            int p = l15;
            float u0 = ha[0][0] + b4[0], u1 = ha[0][1] + b4[1], u2 = ha[0][2] + b4[2];
            u_out[(wp0 + p) * 3 + 0] = u0;
            u_out[(wp0 + p) * 3 + 1] = u1;
            u_out[(wp0 + p) * 3 + 2] = u2;
            float x0 = xw[p * 4 + 0], xp3 = xw[p * 4 + 3];
            float sc = fminf(fmaxf(x0 * (1.f / LFIX), 0.f), 1.f);
            if ((wp0 + p) < nfixv && sc == 0.f)
                ef = xp3 * 0.5f * KFIX * (u0 * u0 + u1 * u1 + u2 * u2);
            float g00 = ha[1][0], g01 = ha[1][1], g02 = ha[1][2];
            float g10 = ha[2][0], g11 = ha[2][1], g12 = ha[2][2];
            float g20 = ha[3][0], g21 = ha[3][1], g22 = ha[3][2];
            float e11 = g11, e22 = g00, e33 = g22;
            float e12 = 0.5f * (g01 + g10);
            float e13 = 0.5f * (g21 + g12);
            float e23 = 0.5f * (g20 + g02);
            float tr = e11 + e22 + e33;
            float en = 0.5f * LAMBDA_L * tr * tr +
                       MU_L * (e11 * e11 + e22 * e22 + e33 * e33 +
                               2.f * (e12 * e12 + e13 * e13 + e23 * e23));
            float exp3 = en * xp3;
            energy_c_out[wp0 + p] = 2.f * exp3;
            er = exp3;
        }
        er = wred(er);
        ef = wred(ef);
        if (lane == 0) {
            atomicAdd(acc + 0, er);
            atomicAdd(acc + 1, ef);
        }

        // ---- exact parameter-Jacobian trace (wave 0 of sampled tiles) ----
        if (do_trace) {
            float nh1 = wnorm(hist, lane);
            float nh2 = wnorm(hist + 16 * HDIM, lane);
            float nh3 = wnorm(sl[0], lane);
            // seeds d3_o = (1-h3^2) * W4[:,o] into sl[1..3]
#pragma unroll
            for (int it = 0; it < 4; ++it) {
                int f = lane + it * 64;
                int p = f >> 4, blk = f & 15, j0 = blk * 8;
                bf16x8 h3v = *(const bf16x8*)(sl[0] + swb(p, blk));
                bf16x8 d0, d1, d2;
#pragma unroll
                for (int e = 0; e < 8; ++e) {
                    float h = (float)h3v[e];
                    float fct = 1.f - h * h;
                    int k = j0 + e;
                    d0[e] = (__bf16)(fct * W4[k * 3 + 0]);
                    d1[e] = (__bf16)(fct * W4[k * 3 + 1]);
                    d2[e] = (__bf16)(fct * W4[k * 3 + 2]);
                }
                int wi = swb(p, blk);
                *(bf16x8*)(sl[1] + wi) = d0;
                *(bf16x8*)(sl[2] + wi) = d1;
                *(bf16x8*)(sl[3] + wi) = d2;
            }
            __bf16* tb[3] = {sl[1], sl[2], sl[3]};
            float s3 = wnorm(sl[1], lane) + wnorm(sl[2], lane) + wnorm(sl[3], lane);
            float s_acc = s3 * (1.f + nh2);
            wgemm_bwd<3>(W3, tb, hist + 16 * HDIM, lane);   // delta2
            float s2 = wnorm(sl[1], lane) + wnorm(sl[2], lane) + wnorm(sl[3], lane);
            s_acc += s2 * (1.f + nh1);
            wgemm_bwd<3>(W2, tb, hist, lane);               // delta1
            float s1 = wnorm(sl[1], lane) + wnorm(sl[2], lane) + wnorm(sl[3], lane);
            float su = 0.f, sr = 0.f, cu = 0.f, cr = 0.f;
            if (q == 0) {
                int p = l15;
                float x0 = xw[p * 4 + 0], x1 = xw[p * 4 + 1], x2 = xw[p * 4 + 2];
                float nx = x0 * x0 + x1 * x1 + x2 * x2;
                float s = s_acc + s1 * (1.f + nx) + 3.f * (nh3 + 1.f);
                bool uu = (wp0 + p) < nfixv;
                su = uu ? s : 0.f;
                sr = uu ? 0.f : s;
                cu = uu ? 1.f : 0.f;
                cr = uu ? 0.f : 1.f;
            }
            su = wred(su); sr = wred(sr); cu = wred(cu); cr = wred(cr);
            if (lane == 0) {
                atomicAdd(acc + 3, su);
                atomicAdd(acc + 4, sr);
                atomicAdd(acc + 5, cu);
                atomicAdd(acc + 6, cr);
            }
        }
    } else {
        // ---------------- force tile (wave-private, NB=1) ----------------
#pragma unroll
        for (int it = 0; it < 4; ++it) {
            int f = lane + it * 64;
            int p = f >> 4, blk = f & 15, j0 = blk * 8;
            float x0 = xw[p * 4 + 0], x1 = xw[p * 4 + 1], x2 = xw[p * 4 + 2];
            bf16x8 hv;
#pragma unroll
            for (int jj = 0; jj < 8; ++jj) {
                int j = j0 + jj;
                float z = b1s[j] + x0 * W1s[j] + x1 * W1s[HDIM + j] + x2 * W1s[2 * HDIM + j];
                hv[jj] = (__bf16)fast_tanh(z);
            }
            *(bf16x8*)(sl[0] + swb(p, blk)) = hv;
        }
        wgemm_fwd<1>(W2Ts, sl, b2, lane);
        wgemm_fwd<1>(W3Ts, sl, b3, lane);
        f32x4 ha = (f32x4){0.f, 0.f, 0.f, 0.f};
#pragma unroll
        for (int ks = 0; ks < 4; ++ks) {
            bf16x8 bf_ = *(const bf16x8*)(sl[0] + swb(l15, ks * 4 + q));
            ha = __builtin_amdgcn_mfma_f32_16x16x32_bf16(w4f[ks], bf_, ha, 0, 0, 0);
        }
        float fsum = 0.f;
        if (q == 0) {
            fsum = (ha[0] + b4[0]) * Fv[0] + (ha[1] + b4[1]) * Fv[1] + (ha[2] + b4[2]) * Fv[2];
        }
        fsum = wred(fsum);
        if (lane == 0) atomicAdd(acc + 2, fsum);
    }
}

__global__ void pinn_final(const float* __restrict__ acc, float* __restrict__ out,
                           int Ntot, const int* __restrict__ nfixp) {
    float es = acc[0], ef = acc[1], fl = acc[2];
    float su = acc[3], sr = acc[4], cu = acc[5], cr = acc[6];
    float nfix = (float)nfixp[0];
    float tu = su / fmaxf(cu, 1.f) * nfix;
    float tr = sr / fmaxf(cr, 1.f) * ((float)Ntot - nfix);
    float energy_ans = EMV * (es / (float)Ntot);
    float E_fix = ef * EMV / (float)Ntot;
    float lam = tr / (tu + 1e-12f);
    lam = fminf(fmaxf(lam, 0.001f), 1000.f);
    out[0] = energy_ans - fl + lam * E_fix;
}

extern "C" void kernel_launch(void* const* d_in, const int* in_sizes, int n_in,
                              void* d_out, int out_size, void* d_ws, size_t ws_size,
                              hipStream_t stream) {
    const float* xPhys = (const float*)d_in[0];
    const float* coord = (const float*)d_in[1];
    const float* W1 = (const float*)d_in[2];
    const float* b1 = (const float*)d_in[3];
    const float* W2 = (const float*)d_in[4];
    const float* b2 = (const float*)d_in[5];
    const float* W3 = (const float*)d_in[6];
    const float* b3 = (const float*)d_in[7];
    const float* W4 = (const float*)d_in[8];
    const float* b4 = (const float*)d_in[9];
    const float* fc = (const float*)d_in[10];
    const float* Fv = (const float*)d_in[11];
    const int* nfix = (const int*)d_in[12];

    const int N = in_sizes[0];        // 65536
    const int NF = in_sizes[10] / 3;  // 4096
    float* out = (float*)d_out;
    float* acc = (float*)d_ws;        // [energy, efix, force, su, sr, cnt_u, cnt_r]

    const int nmain = N / TPTS;       // 1024
    const int nforce = NF / TPTS;     // 64
    hipMemsetAsync(acc, 0, 8 * sizeof(float), stream);
    pinn_all<<<dim3(nmain + nforce), dim3(NTHREADS), 0, stream>>>(
        xPhys, coord, W1, b1, W2, b2, W3, b3, W4, b4, fc, Fv, nfix,
        out + 1, out + 1 + N, acc, nmain);
    pinn_final<<<dim3(1), dim3(1), 0, stream>>>(acc, out, N, nfix);
}

// Round 8
// 183.883 us; speedup vs baseline: 1.4132x; 1.4132x over previous
//
#include <hip/hip_runtime.h>
#include <math.h>

typedef __bf16 bf16x8 __attribute__((ext_vector_type(8)));
typedef __bf16 bf16x4 __attribute__((ext_vector_type(4)));
typedef float f32x4 __attribute__((ext_vector_type(4)));

#define HDIM 128
#define PTS 64
#define NTHREADS 256

#define EMV 0.001f
#define LFIX 0.05f
#define KFIX 100.0f
#define LAMBDA_L 0.5769230769230769f
#define MU_L 0.3846153846153846f

// swizzled bf16-unit index of 16B block `blk` (0..15) in row r (rows of 128 bf16)
__device__ __forceinline__ int swb(int r, int blk) {
    return (r << 7) + ((blk ^ (r & 7)) << 3);
}

__device__ __forceinline__ float fast_tanh(float x) {
    float xc = fminf(fmaxf(x, -10.f), 10.f);
    float e = __expf(2.f * xc);
    return 1.f - 2.f * __builtin_amdgcn_rcpf(e + 1.f);
}

__device__ __forceinline__ float wred(float v) {
#pragma unroll
    for (int off = 32; off > 0; off >>= 1) v += __shfl_down(v, off, 64);
    return v;
}

// Wl[n][j] = Wg[j][n]  (transposed), bf16, swizzled.  For forward GEMMs (A = W^T).
__device__ __forceinline__ void stage_wt(const float* __restrict__ Wg, __bf16* Wl, int tid) {
    const int n = tid & 127;
    const int j0base = (tid >> 7) * 64;
#pragma unroll
    for (int jj = 0; jj < 64; jj += 4) {
        int j0 = j0base + jj;
        float a = Wg[(j0 + 0) * HDIM + n];
        float b = Wg[(j0 + 1) * HDIM + n];
        float c = Wg[(j0 + 2) * HDIM + n];
        float d = Wg[(j0 + 3) * HDIM + n];
        bf16x4 pk = {(__bf16)a, (__bf16)b, (__bf16)c, (__bf16)d};
        *(bf16x4*)(Wl + swb(n, j0 >> 3) + (j0 & 7)) = pk;
    }
}

// Wl[j][k] = Wg[j][k]  (row-major), bf16, swizzled.  For backward GEMMs (A = W).
__device__ __forceinline__ void stage_w(const float* __restrict__ Wg, __bf16* Wl, int tid) {
#pragma unroll
    for (int it = 0; it < 8; ++it) {
        int f = tid + it * NTHREADS;  // 2048 blocks of 8 elems
        int j = f >> 4, blk = f & 15;
        const float4* src = (const float4*)(Wg + j * HDIM + blk * 8);
        float4 v0 = src[0], v1 = src[1];
        bf16x8 pk = {(__bf16)v0.x, (__bf16)v0.y, (__bf16)v0.z, (__bf16)v0.w,
                     (__bf16)v1.x, (__bf16)v1.y, (__bf16)v1.z, (__bf16)v1.w};
        *(bf16x8*)(Wl + swb(j, blk)) = pk;
    }
}

// Batched MFMA GEMM: out[b][p][n] = sum_k A[n][k] * in[b][p][k], NB buffers share A.
// A = Wl (LDS, 128x128 bf16 swizzled).  D tile: row=n (from A), col=p (from B).
// EPI 0: buf0 -> tanh(acc+bias) (bf16 out), bufs 1.. -> acc * (1-h^2) with local fp32 h.
// EPI 1: all bufs -> acc * (1 - href[p][n]^2), href read from LDS.
// In-place safe: internal barrier between reads and writes.
template <int NB, int EPI>
__device__ __forceinline__ void mfma_block(const __bf16* __restrict__ Wl,
                                           __bf16* const* inb, __bf16* const* outb,
                                           const float* __restrict__ biasg,
                                           const __bf16* __restrict__ href, int tid) {
    const int lane = tid & 63;
    const int wid = tid >> 6;
    const int l15 = lane & 15;
    const int q = lane >> 4;
    const int rt0 = wid * 2;
    f32x4 acc[NB][2][4];
#pragma unroll
    for (int b = 0; b < NB; ++b)
#pragma unroll
        for (int r = 0; r < 2; ++r)
#pragma unroll
            for (int c = 0; c < 4; ++c) acc[b][r][c] = (f32x4){0.f, 0.f, 0.f, 0.f};

#pragma unroll
    for (int ks = 0; ks < 4; ++ks) {
        const int kb = ks * 4 + q;
        bf16x8 afr[2];
#pragma unroll
        for (int r = 0; r < 2; ++r)
            afr[r] = *(const bf16x8*)(Wl + swb((rt0 + r) * 16 + l15, kb));
#pragma unroll
        for (int b = 0; b < NB; ++b) {
            bf16x8 bfr[4];
#pragma unroll
            for (int c = 0; c < 4; ++c)
                bfr[c] = *(const bf16x8*)(inb[b] + swb(c * 16 + l15, kb));
#pragma unroll
            for (int r = 0; r < 2; ++r)
#pragma unroll
                for (int c = 0; c < 4; ++c)
                    acc[b][r][c] = __builtin_amdgcn_mfma_f32_16x16x32_bf16(
                        afr[r], bfr[c], acc[b][r][c], 0, 0, 0);
        }
    }
    __syncthreads();  // all B reads complete before in-place writes
#pragma unroll
    for (int r = 0; r < 2; ++r) {
        const int n0 = (rt0 + r) * 16 + q * 4;
        float bias4[4];
        if (EPI == 0) {
            float4 bv = *(const float4*)(biasg + n0);
            bias4[0] = bv.x; bias4[1] = bv.y; bias4[2] = bv.z; bias4[3] = bv.w;
        }
#pragma unroll
        for (int c = 0; c < 4; ++c) {
            const int p = c * 16 + l15;
            const int widx = swb(p, n0 >> 3) + (n0 & 7);
            float fct[4];
            if (EPI == 0) {
                bf16x4 hv;
#pragma unroll
                for (int i = 0; i < 4; ++i) {
                    float h = fast_tanh(acc[0][r][c][i] + bias4[i]);
                    hv[i] = (__bf16)h;
                    fct[i] = 1.f - h * h;
                }
                *(bf16x4*)(outb[0] + widx) = hv;
            } else {
                bf16x4 hv = *(const bf16x4*)(href + widx);
#pragma unroll
                for (int i = 0; i < 4; ++i) {
                    float h = (float)hv[i];
                    fct[i] = 1.f - h * h;
                }
            }
            const int bstart = (EPI == 0) ? 1 : 0;
#pragma unroll
            for (int b = bstart; b < NB; ++b) {
                bf16x4 ov;
#pragma unroll
                for (int i = 0; i < 4; ++i) ov[i] = (__bf16)(acc[b][r][c][i] * fct[i]);
                *(bf16x4*)(outb[b] + widx) = ov;
            }
        }
    }
}

// per-(p) partial sum-of-squares of three bf16 buffers -> npart[12][64]
__device__ __forceinline__ void dnorms(const __bf16* a, const __bf16* b, const __bf16* c2,
                                       float* npart, int tid) {
    int p = tid & 63, cc = tid >> 6;
    float s0 = 0.f, s1 = 0.f, s2 = 0.f;
#pragma unroll
    for (int blk = cc * 4; blk < cc * 4 + 4; ++blk) {
        bf16x8 v0 = *(const bf16x8*)(a + swb(p, blk));
        bf16x8 v1 = *(const bf16x8*)(b + swb(p, blk));
        bf16x8 v2 = *(const bf16x8*)(c2 + swb(p, blk));
#pragma unroll
        for (int e = 0; e < 8; ++e) {
            float f0 = (float)v0[e], f1 = (float)v1[e], f2 = (float)v2[e];
            s0 += f0 * f0; s1 += f1 * f1; s2 += f2 * f2;
        }
    }
    npart[(0 + cc) * PTS + p] = s0;
    npart[(4 + cc) * PTS + p] = s1;
    npart[(8 + cc) * PTS + p] = s2;
}

__device__ __forceinline__ float sum12(const float* npart, int p) {
    float d = 0.f;
#pragma unroll
    for (int i = 0; i < 12; ++i) d += npart[i * PTS + p];
    return d;
}

__global__ void __launch_bounds__(NTHREADS) pinn_all(
    const float* __restrict__ xPhys, const float* __restrict__ coord,
    const float* __restrict__ W1, const float* __restrict__ b1,
    const float* __restrict__ W2, const float* __restrict__ b2,
    const float* __restrict__ W3, const float* __restrict__ b3,
    const float* __restrict__ W4, const float* __restrict__ b4,
    const float* __restrict__ fc, const float* __restrict__ Fv,
    const int* __restrict__ nfixp,
    float* __restrict__ energy_c_out, float* __restrict__ u_out,
    float* __restrict__ acc, int nmain) {
    __shared__ __align__(16) __bf16 Wstage[HDIM * HDIM];
    __shared__ __align__(16) __bf16 h1s[PTS * HDIM], h2s[PTS * HDIM], h3s[PTS * HDIM];
    __shared__ __align__(16) __bf16 t0s[PTS * HDIM], t1s[PTS * HDIM], t2s[PTS * HDIM];
    __shared__ __align__(16) __bf16 W4p[16 * HDIM];   // padded W4^T (rows 3..15 zero)
    __shared__ __align__(16) float W4ts[3 * HDIM];    // W4^T fp32
    __shared__ __align__(16) float xss[PTS * 4];
    __shared__ float xp3s[PTS], nh1s[PTS], nh2s[PTS], nh3s[PTS], nxs[PTS], sss[PTS];
    __shared__ float npart[12 * PTS];
    __shared__ float gls[PTS * 12];
    __shared__ float uls[PTS * 4];

    const int tid = threadIdx.x;
    const int lane = tid & 63, wid = tid >> 6, l15 = lane & 15, q = lane >> 4;
    const int bi = blockIdx.x;

    if (bi < nmain) {
        // ================= main path: 64 coord points =================
        const int base = bi * PTS;
        const int nfixv = nfixp[0];
        const bool fullfix = (base + PTS) <= nfixv;
        const bool fullrr = base >= nfixv;
        // trace: ALL fix tiles (tr_uu exact) + 1/16 of rr tiles + any partial tile
        const bool do_trace = fullfix ? true : (fullrr ? ((bi & 15) == 4) : true);

        if (tid < 3 * PTS) xss[(tid / 3) * 4 + (tid % 3)] = coord[base * 3 + tid];
        if (tid < PTS) {
            float xp = xPhys[base + tid];
            xp3s[tid] = xp * xp * xp;
        }
        for (int e = tid; e < 16 * HDIM; e += NTHREADS) {
            int o = e >> 7, k = e & 127;
            float v = (o < 3) ? W4[k * 3 + o] : 0.f;
            W4p[swb(o, k >> 3) + (k & 7)] = (__bf16)v;
            if (o < 3) W4ts[o * HDIM + k] = v;
        }
        __syncthreads();

        // layer 1 (fp32) -> h1 bf16; tangent seeds t_i = (1-h^2)*W1[i] (fp32 factor)
#pragma unroll
        for (int it = 0; it < 4; ++it) {
            int f = tid + it * NTHREADS;
            int p = f >> 4, blk = f & 15, j0 = blk * 8;
            float x0 = xss[p * 4], x1 = xss[p * 4 + 1], x2 = xss[p * 4 + 2];
            bf16x8 hv, t0v, t1v, t2v;
#pragma unroll
            for (int jj = 0; jj < 8; ++jj) {
                int j = j0 + jj;
                float w0 = W1[j], w1 = W1[HDIM + j], w2 = W1[2 * HDIM + j];
                float z = b1[j] + x0 * w0 + x1 * w1 + x2 * w2;
                float h = fast_tanh(z);
                float fct = 1.f - h * h;
                hv[jj] = (__bf16)h;
                t0v[jj] = (__bf16)(fct * w0);
                t1v[jj] = (__bf16)(fct * w1);
                t2v[jj] = (__bf16)(fct * w2);
            }
            int wi = swb(p, blk);
            *(bf16x8*)(h1s + wi) = hv;
            *(bf16x8*)(t0s + wi) = t0v;
            *(bf16x8*)(t1s + wi) = t1v;
            *(bf16x8*)(t2s + wi) = t2v;
        }
        stage_wt(W2, Wstage, tid);
        __syncthreads();

        {  // layer 2: forward + 3 tangents, shared weight fragments
            __bf16* ib[4] = {h1s, t0s, t1s, t2s};
            __bf16* ob[4] = {h2s, t0s, t1s, t2s};
            mfma_block<4, 0>(Wstage, ib, ob, b2, nullptr, tid);
        }
        __syncthreads();
        stage_wt(W3, Wstage, tid);
        __syncthreads();
        {  // layer 3
            __bf16* ib[4] = {h2s, t0s, t1s, t2s};
            __bf16* ob[4] = {h3s, t0s, t1s, t2s};
            mfma_block<4, 0>(Wstage, ib, ob, b3, nullptr, tid);
        }
        __syncthreads();

        {  // head: u = h3@W4+b4 and J columns g[i][o] = t_i@W4, via padded-W4 MFMA
            __bf16* bl[4] = {h3s, t0s, t1s, t2s};
            f32x4 ha[4];
#pragma unroll
            for (int b = 0; b < 4; ++b) ha[b] = (f32x4){0.f, 0.f, 0.f, 0.f};
#pragma unroll
            for (int ks = 0; ks < 4; ++ks) {
                int kb = ks * 4 + q;
                bf16x8 af = *(const bf16x8*)(W4p + swb(l15, kb));
#pragma unroll
                for (int b = 0; b < 4; ++b) {
                    bf16x8 bf_ = *(const bf16x8*)(bl[b] + swb(wid * 16 + l15, kb));
                    ha[b] = __builtin_amdgcn_mfma_f32_16x16x32_bf16(af, bf_, ha[b], 0, 0, 0);
                }
            }
            if (q == 0) {  // rows 0..3 of D -> outputs o=0..2
                int p = wid * 16 + l15;
#pragma unroll
                for (int o = 0; o < 3; ++o) {
                    float uv = ha[0][o] + b4[o];
                    uls[p * 4 + o] = uv;
                    u_out[(base + p) * 3 + o] = uv;
                }
#pragma unroll
                for (int b = 1; b < 4; ++b)
#pragma unroll
                    for (int o = 0; o < 3; ++o) gls[p * 12 + (b - 1) * 3 + o] = ha[b][o];
            }
        }
        __syncthreads();

        // E_fix + strain energy (always; wave 0)
        if (tid < PTS) {
            int p = tid;
            float x0 = xss[p * 4];
            float sc = fminf(fmaxf(x0 * (1.f / LFIX), 0.f), 1.f);
            float ef = 0.f;
            if ((base + p) < nfixv && sc == 0.f) {
                float u0 = uls[p * 4], u1 = uls[p * 4 + 1], u2 = uls[p * 4 + 2];
                ef = xp3s[p] * 0.5f * KFIX * (u0 * u0 + u1 * u1 + u2 * u2);
            }
            float g00 = gls[p * 12 + 0], g01 = gls[p * 12 + 1], g02 = gls[p * 12 + 2];
            float g10 = gls[p * 12 + 3], g11 = gls[p * 12 + 4], g12 = gls[p * 12 + 5];
            float g20 = gls[p * 12 + 6], g21 = gls[p * 12 + 7], g22 = gls[p * 12 + 8];
            float e11 = g11, e22 = g00, e33 = g22;
            float e12 = 0.5f * (g01 + g10);
            float e13 = 0.5f * (g21 + g12);
            float e23 = 0.5f * (g20 + g02);
            float tr = e11 + e22 + e33;
            float en = 0.5f * LAMBDA_L * tr * tr +
                       MU_L * (e11 * e11 + e22 * e22 + e33 * e33 +
                               2.f * (e12 * e12 + e13 * e13 + e23 * e23));
            float exp3 = en * xp3s[p];
            energy_c_out[base + p] = 2.f * exp3;
            float er = wred(exp3);
            ef = wred(ef);
            if (tid == 0) {
                atomicAdd(acc + 0, er);
                atomicAdd(acc + 1, ef);
            }
        }

        // ---- exact parameter-Jacobian trace (sampled tiles only) ----
        if (do_trace) {
            // norms of h1,h2,h3
            {
                int p = tid & 63, cc = tid >> 6;
                float a1 = 0.f, a2 = 0.f, a3 = 0.f;
#pragma unroll
                for (int blk = cc * 4; blk < cc * 4 + 4; ++blk) {
                    bf16x8 v1 = *(const bf16x8*)(h1s + swb(p, blk));
                    bf16x8 v2 = *(const bf16x8*)(h2s + swb(p, blk));
                    bf16x8 v3 = *(const bf16x8*)(h3s + swb(p, blk));
#pragma unroll
                    for (int e = 0; e < 8; ++e) {
                        float f1 = (float)v1[e], f2 = (float)v2[e], f3 = (float)v3[e];
                        a1 += f1 * f1; a2 += f2 * f2; a3 += f3 * f3;
                    }
                }
                npart[(0 + cc) * PTS + p] = a1;
                npart[(4 + cc) * PTS + p] = a2;
                npart[(8 + cc) * PTS + p] = a3;
            }
            // delta3 seeds into t0..t2 (tangents no longer needed)
#pragma unroll
            for (int it = 0; it < 4; ++it) {
                int f = tid + it * NTHREADS;
                int p = f >> 4, blk = f & 15, j0 = blk * 8;
                bf16x8 h3v = *(const bf16x8*)(h3s + swb(p, blk));
                bf16x8 d0, d1, d2;
#pragma unroll
                for (int e = 0; e < 8; ++e) {
                    float h = (float)h3v[e];
                    float fct = 1.f - h * h;
                    d0[e] = (__bf16)(fct * W4ts[j0 + e]);
                    d1[e] = (__bf16)(fct * W4ts[HDIM + j0 + e]);
                    d2[e] = (__bf16)(fct * W4ts[2 * HDIM + j0 + e]);
                }
                int wi = swb(p, blk);
                *(bf16x8*)(t0s + wi) = d0;
                *(bf16x8*)(t1s + wi) = d1;
                *(bf16x8*)(t2s + wi) = d2;
            }
            stage_w(W3, Wstage, tid);
            __syncthreads();
            if (tid < PTS) {
                int p = tid;
                nh1s[p] = npart[0 * PTS + p] + npart[1 * PTS + p] + npart[2 * PTS + p] + npart[3 * PTS + p];
                nh2s[p] = npart[4 * PTS + p] + npart[5 * PTS + p] + npart[6 * PTS + p] + npart[7 * PTS + p];
                nh3s[p] = npart[8 * PTS + p] + npart[9 * PTS + p] + npart[10 * PTS + p] + npart[11 * PTS + p];
                float x0 = xss[p * 4], x1 = xss[p * 4 + 1], x2 = xss[p * 4 + 2];
                nxs[p] = x0 * x0 + x1 * x1 + x2 * x2;
            }
            __syncthreads();
            dnorms(t0s, t1s, t2s, npart, tid);  // ||delta3||^2
            __syncthreads();
            if (tid < PTS) sss[tid] = sum12(npart, tid) * (1.f + nh2s[tid]);
            {
                __bf16* ib[3] = {t0s, t1s, t2s};
                mfma_block<3, 1>(Wstage, ib, ib, nullptr, h2s, tid);  // delta2
            }
            __syncthreads();
            dnorms(t0s, t1s, t2s, npart, tid);  // ||delta2||^2
            stage_w(W2, Wstage, tid);
            __syncthreads();
            if (tid < PTS) sss[tid] += sum12(npart, tid) * (1.f + nh1s[tid]);
            {
                __bf16* ib[3] = {t0s, t1s, t2s};
                mfma_block<3, 1>(Wstage, ib, ib, nullptr, h1s, tid);  // delta1
            }
            __syncthreads();
            dnorms(t0s, t1s, t2s, npart, tid);  // ||delta1||^2
            __syncthreads();
            if (tid < PTS) {
                int p = tid;
                float s = sss[p] + sum12(npart, p) * (1.f + nxs[p]) + 3.f * (nh3s[p] + 1.f);
                bool uu = (base + p) < nfixv;
                float su = uu ? s : 0.f;
                float sr = uu ? 0.f : s;
                float cu = uu ? 1.f : 0.f;
                float cr = uu ? 0.f : 1.f;
                su = wred(su); sr = wred(sr); cu = wred(cu); cr = wred(cr);
                if (tid == 0) {
                    atomicAdd(acc + 3, su);
                    atomicAdd(acc + 4, sr);
                    atomicAdd(acc + 5, cu);
                    atomicAdd(acc + 6, cr);
                }
            }
        }
    } else {
        // ================= force path: 64 force points =================
        const int fbase = (bi - nmain) * PTS;
        if (tid < 3 * PTS) xss[(tid / 3) * 4 + (tid % 3)] = fc[fbase * 3 + tid];
        for (int e = tid; e < 16 * HDIM; e += NTHREADS) {
            int o = e >> 7, k = e & 127;
            W4p[swb(o, k >> 3) + (k & 7)] = (__bf16)((o < 3) ? W4[k * 3 + o] : 0.f);
        }
        __syncthreads();
#pragma unroll
        for (int it = 0; it < 4; ++it) {
            int f = tid + it * NTHREADS;
            int p = f >> 4, blk = f & 15, j0 = blk * 8;
            float x0 = xss[p * 4], x1 = xss[p * 4 + 1], x2 = xss[p * 4 + 2];
            bf16x8 hv;
#pragma unroll
            for (int jj = 0; jj < 8; ++jj) {
                int j = j0 + jj;
                float z = b1[j] + x0 * W1[j] + x1 * W1[HDIM + j] + x2 * W1[2 * HDIM + j];
                hv[jj] = (__bf16)fast_tanh(z);
            }
            *(bf16x8*)(h1s + swb(p, blk)) = hv;
        }
        stage_wt(W2, Wstage, tid);
        __syncthreads();
        {
            __bf16* ib[1] = {h1s};
            mfma_block<1, 0>(Wstage, ib, ib, b2, nullptr, tid);
        }
        __syncthreads();
        stage_wt(W3, Wstage, tid);
        __syncthreads();
        {
            __bf16* ib[1] = {h1s};
            mfma_block<1, 0>(Wstage, ib, ib, b3, nullptr, tid);
        }
        __syncthreads();
        {
            f32x4 ha = (f32x4){0.f, 0.f, 0.f, 0.f};
#pragma unroll
            for (int ks = 0; ks < 4; ++ks) {
                int kb = ks * 4 + q;
                bf16x8 af = *(const bf16x8*)(W4p + swb(l15, kb));
                bf16x8 bf_ = *(const bf16x8*)(h1s + swb(wid * 16 + l15, kb));
                ha = __builtin_amdgcn_mfma_f32_16x16x32_bf16(af, bf_, ha, 0, 0, 0);
            }
            if (q == 0) {
                int p = wid * 16 + l15;
#pragma unroll
                for (int o = 0; o < 3; ++o) uls[p * 4 + o] = ha[o] + b4[o];
            }
        }
        __syncthreads();
        if (tid < PTS) {
            float fsum = uls[tid * 4] * Fv[0] + uls[tid * 4 + 1] * Fv[1] + uls[tid * 4 + 2] * Fv[2];
            fsum = wred(fsum);
            if (tid == 0) atomicAdd(acc + 2, fsum);
        }
    }
}

__global__ void pinn_final(const float* __restrict__ acc, float* __restrict__ out,
                           int Ntot, const int* __restrict__ nfixp) {
    float es = acc[0], ef = acc[1], fl = acc[2];
    float su = acc[3], sr = acc[4], cu = acc[5], cr = acc[6];
    float nfix = (float)nfixp[0];
    float tu = su / fmaxf(cu, 1.f) * nfix;
    float tr = sr / fmaxf(cr, 1.f) * ((float)Ntot - nfix);
    float energy_ans = EMV * (es / (float)Ntot);
    float E_fix = ef * EMV / (float)Ntot;
    float lam = tr / (tu + 1e-12f);
    lam = fminf(fmaxf(lam, 0.001f), 1000.f);
    out[0] = energy_ans - fl + lam * E_fix;
}

extern "C" void kernel_launch(void* const* d_in, const int* in_sizes, int n_in,
                              void* d_out, int out_size, void* d_ws, size_t ws_size,
                              hipStream_t stream) {
    const float* xPhys = (const float*)d_in[0];
    const float* coord = (const float*)d_in[1];
    const float* W1 = (const float*)d_in[2];
    const float* b1 = (const float*)d_in[3];
    const float* W2 = (const float*)d_in[4];
    const float* b2 = (const float*)d_in[5];
    const float* W3 = (const float*)d_in[6];
    const float* b3 = (const float*)d_in[7];
    const float* W4 = (const float*)d_in[8];
    const float* b4 = (const float*)d_in[9];
    const float* fc = (const float*)d_in[10];
    const float* Fv = (const float*)d_in[11];
    const int* nfix = (const int*)d_in[12];

    const int N = in_sizes[0];        // 65536
    const int NF = in_sizes[10] / 3;  // 4096
    float* out = (float*)d_out;
    float* acc = (float*)d_ws;  // [energy, efix, force, su, sr, cnt_u, cnt_r]

    const int nmain = N / PTS;        // 1024
    const int nforce = NF / PTS;      // 64
    hipMemsetAsync(acc, 0, 8 * sizeof(float), stream);
    pinn_all<<<dim3(nmain + nforce), dim3(NTHREADS), 0, stream>>>(
        xPhys, coord, W1, b1, W2, b2, W3, b3, W4, b4, fc, Fv, nfix,
        out + 1, out + 1 + N, acc, nmain);
    pinn_final<<<dim3(1), dim3(1), 0, stream>>>(acc, out, N, nfix);
}